// Round 1
// baseline (6135.606 us; speedup 1.0000x reference)
//
#include <hip/hip_runtime.h>
#include <hip/hip_bf16.h>

#define HIDDEN 4096
#define NHEADS 32
#define HEADDIM 128
#define ROT 64
#define BB 2
#define SS 2048
#define NTOK (BB*SS)        // 4096 tokens
#define QKVN (3*HIDDEN)     // 12288

typedef __attribute__((ext_vector_type(8))) short short8;
typedef __attribute__((ext_vector_type(4))) float floatx4;

// ---------------- cast fp32 -> bf16 ----------------
__global__ void cast_bf16_kernel(const float* __restrict__ x,
                                 __hip_bfloat16* __restrict__ y, int n4) {
  int idx = blockIdx.x * blockDim.x + threadIdx.x;
  if (idx >= n4) return;
  float4 v = ((const float4*)x)[idx];
  __hip_bfloat162 a, b;
  a.x = __float2bfloat16(v.x); a.y = __float2bfloat16(v.y);
  b.x = __float2bfloat16(v.z); b.y = __float2bfloat16(v.w);
  ((__hip_bfloat162*)y)[idx * 2]     = a;
  ((__hip_bfloat162*)y)[idx * 2 + 1] = b;
}

// ---------------- MFMA GEMM: C[M,N] = A[M,K](bf16) * B[K,N](fp32->bf16) ----------------
// 128x128 tile, BK=32, 4 waves each owning a 64x64 quadrant (4x4 MFMA 16x16x32).
__device__ inline void store_val(float* p, float v) { *p = v; }
__device__ inline void store_val(__hip_bfloat16* p, float v) { *p = __float2bfloat16(v); }

template <typename OutT>
__global__ __launch_bounds__(256) void gemm_kernel(const __hip_bfloat16* __restrict__ A,
                                                   const float* __restrict__ B,
                                                   OutT* __restrict__ C,
                                                   int M, int N, int K) {
  // LDS: rows padded to 40 bf16 (32+8): keeps b128 alignment, spreads banks (17*dword stride).
  __shared__ __hip_bfloat16 As[128 * 40];   // As[m][k]
  __shared__ __hip_bfloat16 Bs[128 * 40];   // Bs[n][k]  (B transposed)
  const int tid  = threadIdx.x;
  const int wid  = tid >> 6;
  const int lane = tid & 63;
  const int quad = lane >> 4;
  const int l16  = lane & 15;
  const int wm   = (wid >> 1) * 64;
  const int wn   = (wid & 1) * 64;
  const int m0   = blockIdx.y * 128;
  const int n0   = blockIdx.x * 128;

  floatx4 acc[4][4] = {};

  for (int kb = 0; kb < K; kb += 32) {
    __syncthreads();
    // stage A tile 128x32: 2 chunks of 8 bf16 per thread (16B vector copies)
#pragma unroll
    for (int i = 0; i < 2; ++i) {
      int c   = tid + i * 256;            // 0..511
      int row = c >> 2;
      int kc  = (c & 3) * 8;
      short8 av = *(const short8*)(A + (size_t)(m0 + row) * K + kb + kc);
      *(short8*)(As + row * 40 + kc) = av;
    }
    // stage B tile 32x128 transposed -> Bs[n][k], convert fp32->bf16, pack k-pairs
#pragma unroll
    for (int i = 0; i < 8; ++i) {
      int c = tid + i * 256;              // 0..2047
      int n = c & 127;
      int k = (c >> 7) * 2;
      const float* g = B + (size_t)(kb + k) * N + n0 + n;
      __hip_bfloat162 p;
      p.x = __float2bfloat16(g[0]);
      p.y = __float2bfloat16(g[N]);
      *(__hip_bfloat162*)(Bs + n * 40 + k) = p;
    }
    __syncthreads();

    short8 af[4], bf[4];
#pragma unroll
    for (int t = 0; t < 4; ++t)
      af[t] = *(const short8*)(As + (wm + t * 16 + l16) * 40 + quad * 8);
#pragma unroll
    for (int t = 0; t < 4; ++t)
      bf[t] = *(const short8*)(Bs + (wn + t * 16 + l16) * 40 + quad * 8);
#pragma unroll
    for (int mi = 0; mi < 4; ++mi)
#pragma unroll
      for (int ni = 0; ni < 4; ++ni)
        acc[mi][ni] = __builtin_amdgcn_mfma_f32_16x16x32_bf16(af[mi], bf[ni], acc[mi][ni], 0, 0, 0);
  }

  // epilogue: C/D layout row=quad*4+r, col=lane&15 (verified m89/m91)
#pragma unroll
  for (int mi = 0; mi < 4; ++mi)
#pragma unroll
    for (int ni = 0; ni < 4; ++ni)
#pragma unroll
      for (int r = 0; r < 4; ++r) {
        int row = m0 + wm + mi * 16 + quad * 4 + r;
        int col = n0 + wn + ni * 16 + l16;
        store_val(C + (size_t)row * N + col, acc[mi][ni][r]);
      }
}

// ---------------- RoPE (NeoX), in place on q and k halves of qkv ----------------
__global__ void rope_kernel(__hip_bfloat16* __restrict__ qkv,
                            const int* __restrict__ positions) {
  int idx = blockIdx.x * blockDim.x + threadIdx.x;  // B*S*H*(ROT/2) = 4194304
  if (idx >= NTOK * NHEADS * (ROT / 2)) return;
  int i   = idx & 31;          // rotary pair index 0..31
  int h   = (idx >> 5) & 31;
  int tok = idx >> 10;         // b*S + s
  float pos = (float)positions[tok];
  // inv_freq = 10000^(-i/32) = exp(-i * ln(10000)/32)
  float inv_freq = __expf(-(float)i * 0.28782313662425574f);
  float ang = pos * inv_freq;
  float sv, cv;
  sincosf(ang, &sv, &cv);
  size_t base = (size_t)tok * QKVN + h * HEADDIM + i;
  // q
  {
    float x1 = __bfloat162float(qkv[base]);
    float x2 = __bfloat162float(qkv[base + 32]);
    qkv[base]      = __float2bfloat16(x1 * cv - x2 * sv);
    qkv[base + 32] = __float2bfloat16(x2 * cv + x1 * sv);
  }
  // k (columns offset by HIDDEN)
  {
    float x1 = __bfloat162float(qkv[base + HIDDEN]);
    float x2 = __bfloat162float(qkv[base + HIDDEN + 32]);
    qkv[base + HIDDEN]      = __float2bfloat16(x1 * cv - x2 * sv);
    qkv[base + HIDDEN + 32] = __float2bfloat16(x2 * cv + x1 * sv);
  }
}

// ---------------- scalar flash attention, 32 q-rows x 32-key tiles ----------------
// thread t: row i = t>>3 within tile, group g8 = t&7.
// scores phase: g8 indexes 4 key-cols; PV phase: g8 indexes 16-wide d-slice.
// per-row m,l live in registers, replicated across the row's 8 lanes (same wave).
__global__ __launch_bounds__(256) void attn_kernel(const __hip_bfloat16* __restrict__ qkv,
                                                   __hip_bfloat16* __restrict__ out) {
  __shared__ __attribute__((aligned(16))) float Qs[32 * 132];
  __shared__ __attribute__((aligned(16))) float Ks[32 * 132];
  __shared__ __attribute__((aligned(16))) float Vs[32 * 128];
  __shared__ float Ps[32 * 32];

  const int tid = threadIdx.x;
  const int qt  = blockIdx.x & 63;
  const int h   = (blockIdx.x >> 6) & 31;
  const int b   = blockIdx.x >> 11;
  const int tok0 = b * SS + qt * 32;
  const int i   = tid >> 3;
  const int g8  = tid & 7;

  const float scale = 0.08838834764831843f;  // 1/sqrt(128), folded into Q
#pragma unroll
  for (int c = 0; c < 16; ++c) {
    int e = tid + c * 256;
    int r = e >> 7, d = e & 127;
    Qs[r * 132 + d] = scale * __bfloat162float(qkv[(size_t)(tok0 + r) * QKVN + h * HEADDIM + d]);
  }

  float m_r = -INFINITY, l_r = 0.f;
  float O[16];
#pragma unroll
  for (int z = 0; z < 16; ++z) O[z] = 0.f;

  for (int kt = 0; kt <= qt; ++kt) {
    __syncthreads();  // previous tile fully consumed
    int ktok = b * SS + kt * 32;
#pragma unroll
    for (int c = 0; c < 16; ++c) {
      int e = tid + c * 256;
      int r = e >> 7, d = e & 127;
      size_t rowoff = (size_t)(ktok + r) * QKVN + h * HEADDIM + d;
      Ks[r * 132 + d] = __bfloat162float(qkv[rowoff + HIDDEN]);
      Vs[r * 128 + d] = __bfloat162float(qkv[rowoff + 2 * HIDDEN]);
    }
    __syncthreads();

    // ---- scores: s[i][j0..j0+3] ----
    const int j0 = g8 * 4;
    float s0 = 0.f, s1 = 0.f, s2 = 0.f, s3 = 0.f;
    for (int d4 = 0; d4 < 32; ++d4) {
      float4 q4 = *(const float4*)(Qs + i * 132 + d4 * 4);
      float4 k0v = *(const float4*)(Ks + (j0 + 0) * 132 + d4 * 4);
      float4 k1v = *(const float4*)(Ks + (j0 + 1) * 132 + d4 * 4);
      float4 k2v = *(const float4*)(Ks + (j0 + 2) * 132 + d4 * 4);
      float4 k3v = *(const float4*)(Ks + (j0 + 3) * 132 + d4 * 4);
      s0 += q4.x * k0v.x + q4.y * k0v.y + q4.z * k0v.z + q4.w * k0v.w;
      s1 += q4.x * k1v.x + q4.y * k1v.y + q4.z * k1v.z + q4.w * k1v.w;
      s2 += q4.x * k2v.x + q4.y * k2v.y + q4.z * k2v.z + q4.w * k2v.w;
      s3 += q4.x * k3v.x + q4.y * k3v.y + q4.z * k3v.z + q4.w * k3v.w;
    }
    float s[4] = {s0, s1, s2, s3};
    int qg = qt * 32 + i;
#pragma unroll
    for (int jj = 0; jj < 4; ++jj) {
      int kg = kt * 32 + j0 + jj;
      if (kg > qg) s[jj] = -INFINITY;
    }
    // row reduction across the 8 lanes of row i
    float mloc = fmaxf(fmaxf(s[0], s[1]), fmaxf(s[2], s[3]));
    mloc = fmaxf(mloc, __shfl_xor(mloc, 1));
    mloc = fmaxf(mloc, __shfl_xor(mloc, 2));
    mloc = fmaxf(mloc, __shfl_xor(mloc, 4));
    float m_new = fmaxf(m_r, mloc);
    float alpha = __expf(m_r - m_new);  // exp(-inf)=0 on first tile
    float psum = 0.f;
#pragma unroll
    for (int jj = 0; jj < 4; ++jj) {
      float p = __expf(s[jj] - m_new);  // masked -> exp(-inf)=0
      psum += p;
      Ps[i * 32 + j0 + jj] = p;
    }
    psum += __shfl_xor(psum, 1);
    psum += __shfl_xor(psum, 2);
    psum += __shfl_xor(psum, 4);
    l_r = l_r * alpha + psum;
    m_r = m_new;
#pragma unroll
    for (int z = 0; z < 16; ++z) O[z] *= alpha;
    __syncthreads();  // Ps visible

    // ---- PV: O[i][g8*16 .. +16] += P[i][j] * V[j][d] ----
    for (int j = 0; j < 32; ++j) {
      float pj = Ps[i * 32 + j];
      const float* vrow = Vs + j * 128 + g8 * 16;
#pragma unroll
      for (int z4 = 0; z4 < 4; ++z4) {
        float4 v4 = *(const float4*)(vrow + z4 * 4);
        O[z4 * 4 + 0] += pj * v4.x;
        O[z4 * 4 + 1] += pj * v4.y;
        O[z4 * 4 + 2] += pj * v4.z;
        O[z4 * 4 + 3] += pj * v4.w;
      }
    }
  }

  float inv_l = 1.0f / l_r;
  size_t obase = (size_t)(tok0 + i) * HIDDEN + h * HEADDIM + g8 * 16;
#pragma unroll
  for (int z2 = 0; z2 < 8; ++z2) {
    __hip_bfloat162 p2;
    p2.x = __float2bfloat16(O[z2 * 2] * inv_l);
    p2.y = __float2bfloat16(O[z2 * 2 + 1] * inv_l);
    *(__hip_bfloat162*)(out + obase + z2 * 2) = p2;
  }
}

// ---------------- launch ----------------
extern "C" void kernel_launch(void* const* d_in, const int* in_sizes, int n_in,
                              void* d_out, int out_size, void* d_ws, size_t ws_size,
                              hipStream_t stream) {
  const float* hidden    = (const float*)d_in[0];
  const int*   positions = (const int*)d_in[1];
  const float* Wqkv      = (const float*)d_in[2];
  const float* Wout      = (const float*)d_in[3];
  float* out = (float*)d_out;

  // ws layout (bytes): Xb 33.55MB | QKVb 100.66MB | Ab 33.55MB  = 160MB total
  const size_t XB_BYTES   = (size_t)NTOK * HIDDEN * 2;      // 33554432
  const size_t QKV_BYTES  = (size_t)NTOK * QKVN * 2;        // 100663296
  const size_t AB_BYTES   = (size_t)NTOK * HIDDEN * 2;      // 33554432
  if (ws_size < XB_BYTES + QKV_BYTES + AB_BYTES) return;    // fail clean, not segfault

  char* ws = (char*)d_ws;
  __hip_bfloat16* Xb   = (__hip_bfloat16*)ws;
  __hip_bfloat16* QKVb = (__hip_bfloat16*)(ws + XB_BYTES);
  __hip_bfloat16* Ab   = (__hip_bfloat16*)(ws + XB_BYTES + QKV_BYTES);

  // 1. cast hidden fp32 -> bf16
  cast_bf16_kernel<<<(NTOK * HIDDEN / 4 + 255) / 256, 256, 0, stream>>>(
      hidden, Xb, NTOK * HIDDEN / 4);
  // 2. QKV projection: [4096,4096] x [4096,12288] -> bf16
  gemm_kernel<__hip_bfloat16><<<dim3(QKVN / 128, NTOK / 128), 256, 0, stream>>>(
      Xb, Wqkv, QKVb, NTOK, QKVN, HIDDEN);
  // 3. RoPE on q,k
  rope_kernel<<<(NTOK * NHEADS * (ROT / 2) + 255) / 256, 256, 0, stream>>>(QKVb, positions);
  // 4. causal flash attention -> Ab (bf16, [tok, h*128+d] layout)
  attn_kernel<<<BB * NHEADS * (SS / 32), 256, 0, stream>>>(QKVb, Ab);
  // 5. out projection: [4096,4096] x [4096,4096] -> fp32 d_out
  gemm_kernel<float><<<dim3(HIDDEN / 128, NTOK / 128), 256, 0, stream>>>(
      Ab, Wout, out, NTOK, HIDDEN, HIDDEN);
}

// Round 2
// 1646.224 us; speedup vs baseline: 3.7271x; 3.7271x over previous
//
#include <hip/hip_runtime.h>
#include <hip/hip_bf16.h>

#define HIDDEN 4096
#define NHEADS 32
#define HEADDIM 128
#define ROT 64
#define BB 2
#define SS 2048
#define NTOK (BB*SS)        // 4096 tokens
#define QKVN (3*HIDDEN)     // 12288

typedef __attribute__((ext_vector_type(8))) short short8;
typedef __attribute__((ext_vector_type(4))) float floatx4;

// ---------------- cast fp32 -> bf16 ----------------
__global__ void cast_bf16_kernel(const float* __restrict__ x,
                                 __hip_bfloat16* __restrict__ y, int n4) {
  int idx = blockIdx.x * blockDim.x + threadIdx.x;
  if (idx >= n4) return;
  float4 v = ((const float4*)x)[idx];
  __hip_bfloat162 a, b;
  a.x = __float2bfloat16(v.x); a.y = __float2bfloat16(v.y);
  b.x = __float2bfloat16(v.z); b.y = __float2bfloat16(v.w);
  ((__hip_bfloat162*)y)[idx * 2]     = a;
  ((__hip_bfloat162*)y)[idx * 2 + 1] = b;
}

// ---------------- MFMA GEMM: C[M,N] = A[M,K](bf16) * B[K,N](fp32->bf16) ----------------
__device__ inline void store_val(float* p, float v) { *p = v; }
__device__ inline void store_val(__hip_bfloat16* p, float v) { *p = __float2bfloat16(v); }

template <typename OutT>
__global__ __launch_bounds__(256) void gemm_kernel(const __hip_bfloat16* __restrict__ A,
                                                   const float* __restrict__ B,
                                                   OutT* __restrict__ C,
                                                   int M, int N, int K) {
  __shared__ __hip_bfloat16 As[128 * 40];   // As[m][k]
  __shared__ __hip_bfloat16 Bs[128 * 40];   // Bs[n][k]  (B transposed)
  const int tid  = threadIdx.x;
  const int wid  = tid >> 6;
  const int lane = tid & 63;
  const int quad = lane >> 4;
  const int l16  = lane & 15;
  const int wm   = (wid >> 1) * 64;
  const int wn   = (wid & 1) * 64;
  const int m0   = blockIdx.y * 128;
  const int n0   = blockIdx.x * 128;

  floatx4 acc[4][4] = {};

  for (int kb = 0; kb < K; kb += 32) {
    __syncthreads();
#pragma unroll
    for (int i = 0; i < 2; ++i) {
      int c   = tid + i * 256;
      int row = c >> 2;
      int kc  = (c & 3) * 8;
      short8 av = *(const short8*)(A + (size_t)(m0 + row) * K + kb + kc);
      *(short8*)(As + row * 40 + kc) = av;
    }
#pragma unroll
    for (int i = 0; i < 8; ++i) {
      int c = tid + i * 256;
      int n = c & 127;
      int k = (c >> 7) * 2;
      const float* g = B + (size_t)(kb + k) * N + n0 + n;
      __hip_bfloat162 p;
      p.x = __float2bfloat16(g[0]);
      p.y = __float2bfloat16(g[N]);
      *(__hip_bfloat162*)(Bs + n * 40 + k) = p;
    }
    __syncthreads();

    short8 af[4], bf[4];
#pragma unroll
    for (int t = 0; t < 4; ++t)
      af[t] = *(const short8*)(As + (wm + t * 16 + l16) * 40 + quad * 8);
#pragma unroll
    for (int t = 0; t < 4; ++t)
      bf[t] = *(const short8*)(Bs + (wn + t * 16 + l16) * 40 + quad * 8);
#pragma unroll
    for (int mi = 0; mi < 4; ++mi)
#pragma unroll
      for (int ni = 0; ni < 4; ++ni)
        acc[mi][ni] = __builtin_amdgcn_mfma_f32_16x16x32_bf16(af[mi], bf[ni], acc[mi][ni], 0, 0, 0);
  }

#pragma unroll
  for (int mi = 0; mi < 4; ++mi)
#pragma unroll
    for (int ni = 0; ni < 4; ++ni)
#pragma unroll
      for (int r = 0; r < 4; ++r) {
        int row = m0 + wm + mi * 16 + quad * 4 + r;
        int col = n0 + wn + ni * 16 + l16;
        store_val(C + (size_t)row * N + col, acc[mi][ni][r]);
      }
}

// ---------------- RoPE (NeoX), in place on q and k halves of qkv ----------------
__global__ void rope_kernel(__hip_bfloat16* __restrict__ qkv,
                            const int* __restrict__ positions) {
  int idx = blockIdx.x * blockDim.x + threadIdx.x;
  if (idx >= NTOK * NHEADS * (ROT / 2)) return;
  int i   = idx & 31;
  int h   = (idx >> 5) & 31;
  int tok = idx >> 10;
  float pos = (float)positions[tok];
  float inv_freq = __expf(-(float)i * 0.28782313662425574f);
  float ang = pos * inv_freq;
  float sv, cv;
  sincosf(ang, &sv, &cv);
  size_t base = (size_t)tok * QKVN + h * HEADDIM + i;
  {
    float x1 = __bfloat162float(qkv[base]);
    float x2 = __bfloat162float(qkv[base + 32]);
    qkv[base]      = __float2bfloat16(x1 * cv - x2 * sv);
    qkv[base + 32] = __float2bfloat16(x2 * cv + x1 * sv);
  }
  {
    float x1 = __bfloat162float(qkv[base + HIDDEN]);
    float x2 = __bfloat162float(qkv[base + HIDDEN + 32]);
    qkv[base + HIDDEN]      = __float2bfloat16(x1 * cv - x2 * sv);
    qkv[base + HIDDEN + 32] = __float2bfloat16(x2 * cv + x1 * sv);
  }
}

// ---------------- MFMA flash attention ----------------
// Block: one (b, h, qtile of 64 rows). 4 waves; wave w owns q-rows 16w..16w+15.
// LDS: Ks[64][136] k-major, Vt[128][72] = V^T key-major, QPs = Q staging then P (per-wave).
// Q fragments hoisted to registers (tile-invariant) so Qs space is reused for Ps.
__global__ __launch_bounds__(256) void attn_kernel(const __hip_bfloat16* __restrict__ qkv,
                                                   __hip_bfloat16* __restrict__ out) {
  __shared__ __hip_bfloat16 QPs[64 * 136];  // Q staging; later Ps with stride 72
  __shared__ __hip_bfloat16 Ks[64 * 136];
  __shared__ __hip_bfloat16 Vt[128 * 72];

  const int tid  = threadIdx.x;
  const int wid  = tid >> 6;
  const int lane = tid & 63;
  const int quad = lane >> 4;
  const int l16  = lane & 15;
  const int qt   = 31 - (blockIdx.x & 31);   // big q-tiles dispatch first (tail balance)
  const int h    = (blockIdx.x >> 5) & 31;
  const int b    = blockIdx.x >> 10;
  const int qtok0 = b * SS + qt * 64;
  const float scale = 0.08838834764831843f;  // 1/sqrt(128)

  // ---- stage Q (64x128, stride 136) ----
#pragma unroll
  for (int i = 0; i < 4; ++i) {
    int c = tid + i * 256;          // 0..1023
    int row = c >> 4;
    int dc  = (c & 15) * 8;
    short8 v = *(const short8*)(qkv + (size_t)(qtok0 + row) * QKVN + h * HEADDIM + dc);
    *(short8*)(QPs + row * 136 + dc) = v;
  }
  __syncthreads();
  // ---- hoist Q fragments to registers (A-layout: m=l16, k=quad*8+j) ----
  short8 aq[4];
#pragma unroll
  for (int kc = 0; kc < 4; ++kc)
    aq[kc] = *(const short8*)(QPs + (wid * 16 + l16) * 136 + kc * 32 + quad * 8);

  float m_r[4], l_r[4];
  floatx4 accO[8];
#pragma unroll
  for (int r = 0; r < 4; ++r) { m_r[r] = -INFINITY; l_r[r] = 0.f; }
#pragma unroll
  for (int ni = 0; ni < 8; ++ni) accO[ni] = (floatx4){0.f, 0.f, 0.f, 0.f};

  __hip_bfloat16* Ps = QPs;  // per-wave private rows 16w..16w+15, stride 72

  for (int kt = 0; kt <= qt; ++kt) {
    __syncthreads();  // previous tile's Ks/Vt (and first time: Q frags) consumed
    const int ktok = b * SS + kt * 64;

    // ---- stage K (64x128 k-major, stride 136) ----
#pragma unroll
    for (int i = 0; i < 4; ++i) {
      int c = tid + i * 256;
      int row = c >> 4;
      int dc  = (c & 15) * 8;
      short8 v = *(const short8*)(qkv + (size_t)(ktok + row) * QKVN + HIDDEN + h * HEADDIM + dc);
      *(short8*)(Ks + row * 136 + dc) = v;
    }
    // ---- stage V transposed: Vt[d][key], stride 72, bfloat162 pair-repack ----
    // lane slot c: dp (d-pair 0..63) = bits[2:0]+[8:6], kp (key-pair 0..31) = bits[5:3]+[10:9]
    // LDS write bank = (8*dp + kp) % 32 -> 2 lanes/bank (free); global reads 32B-contiguous.
#pragma unroll
    for (int i = 0; i < 8; ++i) {
      int c  = tid + i * 256;          // 0..2047
      int dp = (c & 7) | ((c >> 3) & 0x38);
      int kp = ((c >> 3) & 7) | ((c >> 6) & 0x18);
      const __hip_bfloat16* g = qkv + (size_t)(ktok + 2 * kp) * QKVN + 2 * HIDDEN + h * HEADDIM + 2 * dp;
      __hip_bfloat162 v0 = *(const __hip_bfloat162*)g;
      __hip_bfloat162 v1 = *(const __hip_bfloat162*)(g + QKVN);
      __hip_bfloat162 w0, w1;
      w0.x = v0.x; w0.y = v1.x;
      w1.x = v0.y; w1.y = v1.y;
      *(__hip_bfloat162*)(Vt + (2 * dp) * 72 + 2 * kp)     = w0;
      *(__hip_bfloat162*)(Vt + (2 * dp + 1) * 72 + 2 * kp) = w1;
    }
    __syncthreads();

    // ---- QK^T: wave w rows 16w..+15 x 64 keys ----
    floatx4 accS[4] = {};
#pragma unroll
    for (int ni = 0; ni < 4; ++ni)
#pragma unroll
      for (int kc = 0; kc < 4; ++kc) {
        short8 bk = *(const short8*)(Ks + (16 * ni + l16) * 136 + kc * 32 + quad * 8);
        accS[ni] = __builtin_amdgcn_mfma_f32_16x16x32_bf16(aq[kc], bk, accS[ni], 0, 0, 0);
      }

    // ---- online softmax (C-layout: row=quad*4+r, col=16*ni+l16) ----
    float sv[4][4];
#pragma unroll
    for (int ni = 0; ni < 4; ++ni)
#pragma unroll
      for (int r = 0; r < 4; ++r) sv[ni][r] = accS[ni][r] * scale;
    if (kt == qt) {
#pragma unroll
      for (int ni = 0; ni < 4; ++ni)
#pragma unroll
        for (int r = 0; r < 4; ++r)
          if (16 * ni + l16 > wid * 16 + quad * 4 + r) sv[ni][r] = -INFINITY;
    }
#pragma unroll
    for (int r = 0; r < 4; ++r) {
      float mx = fmaxf(fmaxf(sv[0][r], sv[1][r]), fmaxf(sv[2][r], sv[3][r]));
      mx = fmaxf(mx, __shfl_xor(mx, 1));
      mx = fmaxf(mx, __shfl_xor(mx, 2));
      mx = fmaxf(mx, __shfl_xor(mx, 4));
      mx = fmaxf(mx, __shfl_xor(mx, 8));
      float mnew  = fmaxf(m_r[r], mx);
      float alpha = __expf(m_r[r] - mnew);
      float psum = 0.f;
#pragma unroll
      for (int ni = 0; ni < 4; ++ni) {
        float p = __expf(sv[ni][r] - mnew);
        psum += p;
        Ps[(wid * 16 + quad * 4 + r) * 72 + 16 * ni + l16] = __float2bfloat16(p);
      }
      psum += __shfl_xor(psum, 1);
      psum += __shfl_xor(psum, 2);
      psum += __shfl_xor(psum, 4);
      psum += __shfl_xor(psum, 8);
      l_r[r] = l_r[r] * alpha + psum;
      m_r[r] = mnew;
#pragma unroll
      for (int ni = 0; ni < 8; ++ni) accO[ni][r] *= alpha;
    }
    // no barrier: Ps rows are wave-private (write->read same wave, lgkmcnt handles it)

    // ---- PV: O[16w..+15][128] += P * V  (A=Ps rows, B=Vt rows=d cols) ----
    short8 ap[2];
#pragma unroll
    for (int kc = 0; kc < 2; ++kc)
      ap[kc] = *(const short8*)(Ps + (wid * 16 + l16) * 72 + kc * 32 + quad * 8);
#pragma unroll
    for (int ni = 0; ni < 8; ++ni)
#pragma unroll
      for (int kc = 0; kc < 2; ++kc) {
        short8 bv = *(const short8*)(Vt + (16 * ni + l16) * 72 + kc * 32 + quad * 8);
        accO[ni] = __builtin_amdgcn_mfma_f32_16x16x32_bf16(ap[kc], bv, accO[ni], 0, 0, 0);
      }
  }

  // ---- epilogue ----
  float inv_l[4];
#pragma unroll
  for (int r = 0; r < 4; ++r) inv_l[r] = 1.0f / l_r[r];
#pragma unroll
  for (int ni = 0; ni < 8; ++ni)
#pragma unroll
    for (int r = 0; r < 4; ++r) {
      int row = qtok0 + wid * 16 + quad * 4 + r;
      int col = h * HEADDIM + 16 * ni + l16;
      out[(size_t)row * HIDDEN + col] = __float2bfloat16(accO[ni][r] * inv_l[r]);
    }
}

// ---------------- launch ----------------
extern "C" void kernel_launch(void* const* d_in, const int* in_sizes, int n_in,
                              void* d_out, int out_size, void* d_ws, size_t ws_size,
                              hipStream_t stream) {
  const float* hidden    = (const float*)d_in[0];
  const int*   positions = (const int*)d_in[1];
  const float* Wqkv      = (const float*)d_in[2];
  const float* Wout      = (const float*)d_in[3];
  float* out = (float*)d_out;

  const size_t XB_BYTES   = (size_t)NTOK * HIDDEN * 2;
  const size_t QKV_BYTES  = (size_t)NTOK * QKVN * 2;
  const size_t AB_BYTES   = (size_t)NTOK * HIDDEN * 2;
  if (ws_size < XB_BYTES + QKV_BYTES + AB_BYTES) return;

  char* ws = (char*)d_ws;
  __hip_bfloat16* Xb   = (__hip_bfloat16*)ws;
  __hip_bfloat16* QKVb = (__hip_bfloat16*)(ws + XB_BYTES);
  __hip_bfloat16* Ab   = (__hip_bfloat16*)(ws + XB_BYTES + QKV_BYTES);

  cast_bf16_kernel<<<(NTOK * HIDDEN / 4 + 255) / 256, 256, 0, stream>>>(
      hidden, Xb, NTOK * HIDDEN / 4);
  gemm_kernel<__hip_bfloat16><<<dim3(QKVN / 128, NTOK / 128), 256, 0, stream>>>(
      Xb, Wqkv, QKVb, NTOK, QKVN, HIDDEN);
  rope_kernel<<<(NTOK * NHEADS * (ROT / 2) + 255) / 256, 256, 0, stream>>>(QKVb, positions);
  attn_kernel<<<BB * NHEADS * (SS / 64), 256, 0, stream>>>(QKVb, Ab);
  gemm_kernel<float><<<dim3(HIDDEN / 128, NTOK / 128), 256, 0, stream>>>(
      Ab, Wout, out, NTOK, HIDDEN, HIDDEN);
}

// Round 3
// 1459.319 us; speedup vs baseline: 4.2044x; 1.1281x over previous
//
#include <hip/hip_runtime.h>
#include <hip/hip_bf16.h>
#include <stdint.h>

#define HIDDEN 4096
#define NHEADS 32
#define HEADDIM 128
#define ROT 64
#define BB 2
#define SS 2048
#define NTOK (BB*SS)        // 4096 tokens
#define QKVN (3*HIDDEN)     // 12288

typedef __attribute__((ext_vector_type(8))) short short8;
typedef __attribute__((ext_vector_type(4))) float floatx4;

// ---------------- async global->LDS 16B (wave-uniform LDS base + lane*16) ----------------
__device__ __forceinline__ void async16(const __hip_bfloat16* g, unsigned lds_byte_addr) {
  __builtin_amdgcn_global_load_lds(
      (const __attribute__((address_space(1))) unsigned int*)(uintptr_t)g,
      (__attribute__((address_space(3))) unsigned int*)(uintptr_t)(uint64_t)lds_byte_addr,
      16, 0, 0);
}

// ---------------- cast fp32 -> bf16 ----------------
__global__ void cast_bf16_kernel(const float* __restrict__ x,
                                 __hip_bfloat16* __restrict__ y, int n4) {
  int idx = blockIdx.x * blockDim.x + threadIdx.x;
  if (idx >= n4) return;
  float4 v = ((const float4*)x)[idx];
  __hip_bfloat162 a, b;
  a.x = __float2bfloat16(v.x); a.y = __float2bfloat16(v.y);
  b.x = __float2bfloat16(v.z); b.y = __float2bfloat16(v.w);
  ((__hip_bfloat162*)y)[idx * 2]     = a;
  ((__hip_bfloat162*)y)[idx * 2 + 1] = b;
}

// ---------------- transpose+cast: Wt[n][k] (bf16) = W[k][n_off+n] (fp32, row stride ldn) ----
// block = 256 threads = 256 columns; 32 k-rows per block. Reads coalesced (1KB/row-pass);
// writes 64B contiguous per thread.
__global__ void transpose_cast_kernel(const float* __restrict__ W,
                                      __hip_bfloat16* __restrict__ Wt,
                                      int K, int ldn, int n_off) {
  int n  = blockIdx.x * 256 + threadIdx.x;
  int k0 = blockIdx.y * 32;
  const float* src = W + (size_t)k0 * ldn + n_off + n;
  short8 outv[4];
#pragma unroll
  for (int i = 0; i < 4; ++i) {
#pragma unroll
    for (int j = 0; j < 8; ++j) {
      __hip_bfloat16 b = __float2bfloat16(src[(size_t)(i * 8 + j) * ldn]);
      outv[i][j] = *reinterpret_cast<short*>(&b);
    }
  }
  __hip_bfloat16* dst = Wt + (size_t)n * K + k0;
#pragma unroll
  for (int i = 0; i < 4; ++i) *(short8*)(dst + i * 8) = outv[i];
}

// ---------------- m97-style MFMA GEMM: C[M,n0..] = A[M][K] * Bt[N][K]^T ----------------
// 128x128 tile, BK=32, both operands staged via global_load_lds width-16 into
// UNPADDED k-major LDS (row = 32 bf16 = 64B). 4 waves x (64x64 quadrant) x 4x4 MFMA.
__device__ inline void store_val(float* p, float v) { *p = v; }
__device__ inline void store_val(__hip_bfloat16* p, float v) { *p = __float2bfloat16(v); }

template <typename OutT>
__global__ __launch_bounds__(256) void gemm_bt_kernel(const __hip_bfloat16* __restrict__ A,
                                                      const __hip_bfloat16* __restrict__ Bt,
                                                      OutT* __restrict__ C,
                                                      int M, int K, int ldc) {
  __shared__ __hip_bfloat16 As[128 * 32];
  __shared__ __hip_bfloat16 Bs[128 * 32];
  const int tid  = threadIdx.x;
  const int wid  = tid >> 6;
  const int lane = tid & 63;
  const int quad = lane >> 4;
  const int l16  = lane & 15;
  const int wm   = (wid >> 1) * 64;
  const int wn   = (wid & 1) * 64;
  const int m0   = blockIdx.y * 128;
  const int n0   = blockIdx.x * 128;

  const int srow = lane >> 2;        // lane i covers row i>>2 of its 16-row block
  const int scol = (lane & 3) * 8;   // and elems (i&3)*8 .. +7

  const unsigned as0 = (unsigned)(uintptr_t)(&As[0]);
  const unsigned bs0 = (unsigned)(uintptr_t)(&Bs[0]);

  floatx4 acc[4][4] = {};

  for (int kb = 0; kb < K; kb += 32) {
    __syncthreads();
    // stage A & B tiles: per wave 2+2 global_load_lds_dwordx4 (16 rows x 64B each)
#pragma unroll
    for (int j = 0; j < 2; ++j) {
      int rblk = wid * 32 + j * 16;
      unsigned la = __builtin_amdgcn_readfirstlane(as0 + rblk * 64);
      async16(A + (size_t)(m0 + rblk + srow) * K + kb + scol, la);
      unsigned lb = __builtin_amdgcn_readfirstlane(bs0 + rblk * 64);
      async16(Bt + (size_t)(n0 + rblk + srow) * K + kb + scol, lb);
    }
    __syncthreads();  // compiler emits s_waitcnt vmcnt(0) before barrier

    short8 af[4], bf[4];
#pragma unroll
    for (int t = 0; t < 4; ++t)
      af[t] = *(const short8*)(As + (wm + t * 16 + l16) * 32 + quad * 8);
#pragma unroll
    for (int t = 0; t < 4; ++t)
      bf[t] = *(const short8*)(Bs + (wn + t * 16 + l16) * 32 + quad * 8);
#pragma unroll
    for (int mi = 0; mi < 4; ++mi)
#pragma unroll
      for (int ni = 0; ni < 4; ++ni)
        acc[mi][ni] = __builtin_amdgcn_mfma_f32_16x16x32_bf16(af[mi], bf[ni], acc[mi][ni], 0, 0, 0);
  }

  // epilogue: C/D layout row=quad*4+r, col=lane&15 (verified m89/m91)
#pragma unroll
  for (int mi = 0; mi < 4; ++mi)
#pragma unroll
    for (int ni = 0; ni < 4; ++ni)
#pragma unroll
      for (int r = 0; r < 4; ++r) {
        int row = m0 + wm + mi * 16 + quad * 4 + r;
        int col = n0 + wn + ni * 16 + l16;
        store_val(C + (size_t)row * ldc + col, acc[mi][ni][r]);
      }
}

// ---------------- RoPE (NeoX), in place on q and k halves of qkv ----------------
__global__ void rope_kernel(__hip_bfloat16* __restrict__ qkv,
                            const int* __restrict__ positions) {
  int idx = blockIdx.x * blockDim.x + threadIdx.x;
  if (idx >= NTOK * NHEADS * (ROT / 2)) return;
  int i   = idx & 31;
  int h   = (idx >> 5) & 31;
  int tok = idx >> 10;
  float pos = (float)positions[tok];
  float inv_freq = __expf(-(float)i * 0.28782313662425574f);
  float ang = pos * inv_freq;
  float sv, cv;
  sincosf(ang, &sv, &cv);
  size_t base = (size_t)tok * QKVN + h * HEADDIM + i;
  {
    float x1 = __bfloat162float(qkv[base]);
    float x2 = __bfloat162float(qkv[base + 32]);
    qkv[base]      = __float2bfloat16(x1 * cv - x2 * sv);
    qkv[base + 32] = __float2bfloat16(x2 * cv + x1 * sv);
  }
  {
    float x1 = __bfloat162float(qkv[base + HIDDEN]);
    float x2 = __bfloat162float(qkv[base + HIDDEN + 32]);
    qkv[base + HIDDEN]      = __float2bfloat16(x1 * cv - x2 * sv);
    qkv[base + HIDDEN + 32] = __float2bfloat16(x2 * cv + x1 * sv);
  }
}

// ---------------- MFMA flash attention (unchanged from R2, verified) ----------------
__global__ __launch_bounds__(256) void attn_kernel(const __hip_bfloat16* __restrict__ qkv,
                                                   __hip_bfloat16* __restrict__ out) {
  __shared__ __hip_bfloat16 QPs[64 * 136];
  __shared__ __hip_bfloat16 Ks[64 * 136];
  __shared__ __hip_bfloat16 Vt[128 * 72];

  const int tid  = threadIdx.x;
  const int wid  = tid >> 6;
  const int lane = tid & 63;
  const int quad = lane >> 4;
  const int l16  = lane & 15;
  const int qt   = 31 - (blockIdx.x & 31);
  const int h    = (blockIdx.x >> 5) & 31;
  const int b    = blockIdx.x >> 10;
  const int qtok0 = b * SS + qt * 64;
  const float scale = 0.08838834764831843f;

#pragma unroll
  for (int i = 0; i < 4; ++i) {
    int c = tid + i * 256;
    int row = c >> 4;
    int dc  = (c & 15) * 8;
    short8 v = *(const short8*)(qkv + (size_t)(qtok0 + row) * QKVN + h * HEADDIM + dc);
    *(short8*)(QPs + row * 136 + dc) = v;
  }
  __syncthreads();
  short8 aq[4];
#pragma unroll
  for (int kc = 0; kc < 4; ++kc)
    aq[kc] = *(const short8*)(QPs + (wid * 16 + l16) * 136 + kc * 32 + quad * 8);

  float m_r[4], l_r[4];
  floatx4 accO[8];
#pragma unroll
  for (int r = 0; r < 4; ++r) { m_r[r] = -INFINITY; l_r[r] = 0.f; }
#pragma unroll
  for (int ni = 0; ni < 8; ++ni) accO[ni] = (floatx4){0.f, 0.f, 0.f, 0.f};

  __hip_bfloat16* Ps = QPs;

  for (int kt = 0; kt <= qt; ++kt) {
    __syncthreads();
    const int ktok = b * SS + kt * 64;

#pragma unroll
    for (int i = 0; i < 4; ++i) {
      int c = tid + i * 256;
      int row = c >> 4;
      int dc  = (c & 15) * 8;
      short8 v = *(const short8*)(qkv + (size_t)(ktok + row) * QKVN + HIDDEN + h * HEADDIM + dc);
      *(short8*)(Ks + row * 136 + dc) = v;
    }
#pragma unroll
    for (int i = 0; i < 8; ++i) {
      int c  = tid + i * 256;
      int dp = (c & 7) | ((c >> 3) & 0x38);
      int kp = ((c >> 3) & 7) | ((c >> 6) & 0x18);
      const __hip_bfloat16* g = qkv + (size_t)(ktok + 2 * kp) * QKVN + 2 * HIDDEN + h * HEADDIM + 2 * dp;
      __hip_bfloat162 v0 = *(const __hip_bfloat162*)g;
      __hip_bfloat162 v1 = *(const __hip_bfloat162*)(g + QKVN);
      __hip_bfloat162 w0, w1;
      w0.x = v0.x; w0.y = v1.x;
      w1.x = v0.y; w1.y = v1.y;
      *(__hip_bfloat162*)(Vt + (2 * dp) * 72 + 2 * kp)     = w0;
      *(__hip_bfloat162*)(Vt + (2 * dp + 1) * 72 + 2 * kp) = w1;
    }
    __syncthreads();

    floatx4 accS[4] = {};
#pragma unroll
    for (int ni = 0; ni < 4; ++ni)
#pragma unroll
      for (int kc = 0; kc < 4; ++kc) {
        short8 bk = *(const short8*)(Ks + (16 * ni + l16) * 136 + kc * 32 + quad * 8);
        accS[ni] = __builtin_amdgcn_mfma_f32_16x16x32_bf16(aq[kc], bk, accS[ni], 0, 0, 0);
      }

    float sv[4][4];
#pragma unroll
    for (int ni = 0; ni < 4; ++ni)
#pragma unroll
      for (int r = 0; r < 4; ++r) sv[ni][r] = accS[ni][r] * scale;
    if (kt == qt) {
#pragma unroll
      for (int ni = 0; ni < 4; ++ni)
#pragma unroll
        for (int r = 0; r < 4; ++r)
          if (16 * ni + l16 > wid * 16 + quad * 4 + r) sv[ni][r] = -INFINITY;
    }
#pragma unroll
    for (int r = 0; r < 4; ++r) {
      float mx = fmaxf(fmaxf(sv[0][r], sv[1][r]), fmaxf(sv[2][r], sv[3][r]));
      mx = fmaxf(mx, __shfl_xor(mx, 1));
      mx = fmaxf(mx, __shfl_xor(mx, 2));
      mx = fmaxf(mx, __shfl_xor(mx, 4));
      mx = fmaxf(mx, __shfl_xor(mx, 8));
      float mnew  = fmaxf(m_r[r], mx);
      float alpha = __expf(m_r[r] - mnew);
      float psum = 0.f;
#pragma unroll
      for (int ni = 0; ni < 4; ++ni) {
        float p = __expf(sv[ni][r] - mnew);
        psum += p;
        Ps[(wid * 16 + quad * 4 + r) * 72 + 16 * ni + l16] = __float2bfloat16(p);
      }
      psum += __shfl_xor(psum, 1);
      psum += __shfl_xor(psum, 2);
      psum += __shfl_xor(psum, 4);
      psum += __shfl_xor(psum, 8);
      l_r[r] = l_r[r] * alpha + psum;
      m_r[r] = mnew;
#pragma unroll
      for (int ni = 0; ni < 8; ++ni) accO[ni][r] *= alpha;
    }

    short8 ap[2];
#pragma unroll
    for (int kc = 0; kc < 2; ++kc)
      ap[kc] = *(const short8*)(Ps + (wid * 16 + l16) * 72 + kc * 32 + quad * 8);
#pragma unroll
    for (int ni = 0; ni < 8; ++ni)
#pragma unroll
      for (int kc = 0; kc < 2; ++kc) {
        short8 bv = *(const short8*)(Vt + (16 * ni + l16) * 72 + kc * 32 + quad * 8);
        accO[ni] = __builtin_amdgcn_mfma_f32_16x16x32_bf16(ap[kc], bv, accO[ni], 0, 0, 0);
      }
  }

  float inv_l[4];
#pragma unroll
  for (int r = 0; r < 4; ++r) inv_l[r] = 1.0f / l_r[r];
#pragma unroll
  for (int ni = 0; ni < 8; ++ni)
#pragma unroll
    for (int r = 0; r < 4; ++r) {
      int row = qtok0 + wid * 16 + quad * 4 + r;
      int col = h * HEADDIM + 16 * ni + l16;
      out[(size_t)row * HIDDEN + col] = __float2bfloat16(accO[ni][r] * inv_l[r]);
    }
}

// ---------------- launch ----------------
extern "C" void kernel_launch(void* const* d_in, const int* in_sizes, int n_in,
                              void* d_out, int out_size, void* d_ws, size_t ws_size,
                              hipStream_t stream) {
  const float* hidden    = (const float*)d_in[0];
  const int*   positions = (const int*)d_in[1];
  const float* Wqkv      = (const float*)d_in[2];
  const float* Wout      = (const float*)d_in[3];
  float* out = (float*)d_out;

  const size_t R0_BYTES      = (size_t)NTOK * HIDDEN * 2;    // 33.55 MB: Xb, later Ab
  const size_t QKV_BYTES     = (size_t)NTOK * QKVN * 2;      // 100.66 MB
  const size_t WT_FULL_BYTES = (size_t)QKVN * HIDDEN * 2;    // 100.66 MB
  const size_t WT_CHUNK_BYTES= (size_t)HIDDEN * HIDDEN * 2;  // 33.55 MB

  const size_t WS_FULL  = R0_BYTES + WT_FULL_BYTES + QKV_BYTES;   // 234.9 MB
  const size_t WS_CHUNK = R0_BYTES + WT_CHUNK_BYTES + QKV_BYTES;  // 167.77 MB (== proven)
  if (ws_size < WS_CHUNK) return;
  const bool full = (ws_size >= WS_FULL);

  char* ws = (char*)d_ws;
  __hip_bfloat16* Xb   = (__hip_bfloat16*)ws;                 // R0
  __hip_bfloat16* Ab   = (__hip_bfloat16*)ws;                 // R0 (aliases Xb, dead by then)
  __hip_bfloat16* Wt   = (__hip_bfloat16*)(ws + R0_BYTES);    // R1 (full or chunk)
  __hip_bfloat16* QKVb = (__hip_bfloat16*)(ws + R0_BYTES + (full ? WT_FULL_BYTES : WT_CHUNK_BYTES));

  // 1. cast hidden fp32 -> bf16
  cast_bf16_kernel<<<(NTOK * HIDDEN / 4 + 255) / 256, 256, 0, stream>>>(
      hidden, Xb, NTOK * HIDDEN / 4);

  // 2. QKV projection
  if (full) {
    transpose_cast_kernel<<<dim3(QKVN / 256, HIDDEN / 32), 256, 0, stream>>>(
        Wqkv, Wt, HIDDEN, QKVN, 0);
    gemm_bt_kernel<__hip_bfloat16><<<dim3(QKVN / 128, NTOK / 128), 256, 0, stream>>>(
        Xb, Wt, QKVb, NTOK, HIDDEN, QKVN);
  } else {
    for (int p = 0; p < 3; ++p) {
      transpose_cast_kernel<<<dim3(HIDDEN / 256, HIDDEN / 32), 256, 0, stream>>>(
          Wqkv, Wt, HIDDEN, QKVN, p * HIDDEN);
      gemm_bt_kernel<__hip_bfloat16><<<dim3(HIDDEN / 128, NTOK / 128), 256, 0, stream>>>(
          Xb, Wt, QKVb + p * HIDDEN, NTOK, HIDDEN, QKVN);
    }
  }

  // 3. RoPE on q,k
  rope_kernel<<<(NTOK * NHEADS * (ROT / 2) + 255) / 256, 256, 0, stream>>>(QKVb, positions);

  // 4. causal flash attention -> Ab (aliases Xb; Xb dead after gemm1)
  attn_kernel<<<BB * NHEADS * (SS / 64), 256, 0, stream>>>(QKVb, Ab);

  // 5. out projection (transpose Wout into Wt region — free after gemm1)
  transpose_cast_kernel<<<dim3(HIDDEN / 256, HIDDEN / 32), 256, 0, stream>>>(
      Wout, Wt, HIDDEN, HIDDEN, 0);
  gemm_bt_kernel<float><<<dim3(HIDDEN / 128, NTOK / 128), 256, 0, stream>>>(
      Ab, Wt, out, NTOK, HIDDEN, HIDDEN);
}